// Round 13
// baseline (1037.722 us; speedup 1.0000x reference)
//
#include <hip/hip_runtime.h>
#include <stdint.h>

#define Bdim 32
#define Tdim 12
#define Vdim 1024
#define Edim 64
#define Gdim 32
#define BT   384   // B*T

typedef __attribute__((ext_vector_type(8))) short bf16x8;
typedef __attribute__((ext_vector_type(4))) float f32x4;

// pk2(a,b): bf16(a) in low 16, bf16(b) in high 16 — single HW instr, RNE.
__device__ __forceinline__ uint pk2(float a, float b) {
    uint r;
    asm("v_cvt_pk_bf16_f32 %0, %1, %2" : "=v"(r) : "v"(a), "v"(b));
    return r;
}
__device__ __forceinline__ ushort f2bf(float f) {
    return (ushort)(pk2(f, f) & 0xffffu);
}

// ---------------------------------------------------------------------------
// K1a: Xbf[e][bt][i] (bf16) = inputs[bt][i][e] (f32).  Pitch 69.
// PROBE: grid x12 (bid = blockIdx.x % 6144) to land in rocprof top-5.
// ---------------------------------------------------------------------------
__global__ __launch_bounds__(256) void k_xpose(const float* __restrict__ in,
                                               ushort* __restrict__ Xbf) {
    __shared__ float tile[64][69];
    const int bid = blockIdx.x % 6144;
    const int bt = bid >> 4;
    const int i0 = (bid & 15) << 6;
    const int r  = threadIdx.x >> 2;     // i-local on load, e on store
    const int q  = threadIdx.x & 3;
    const float* src = in + ((size_t)(bt * Vdim) + i0 + r) * Edim + q * 16;
#pragma unroll
    for (int k = 0; k < 4; ++k) {
        float4 x = *(const float4*)(src + 4 * k);
        tile[r][q * 16 + 4 * k + 0] = x.x;
        tile[r][q * 16 + 4 * k + 1] = x.y;
        tile[r][q * 16 + 4 * k + 2] = x.z;
        tile[r][q * 16 + 4 * k + 3] = x.w;
    }
    __syncthreads();
    const int e  = r;
    const int ib = q * 16;
    uint4 s0, s1;
    s0.x = pk2(tile[ib + 0][e],  tile[ib + 1][e]);
    s0.y = pk2(tile[ib + 2][e],  tile[ib + 3][e]);
    s0.z = pk2(tile[ib + 4][e],  tile[ib + 5][e]);
    s0.w = pk2(tile[ib + 6][e],  tile[ib + 7][e]);
    s1.x = pk2(tile[ib + 8][e],  tile[ib + 9][e]);
    s1.y = pk2(tile[ib + 10][e], tile[ib + 11][e]);
    s1.z = pk2(tile[ib + 12][e], tile[ib + 13][e]);
    s1.w = pk2(tile[ib + 14][e], tile[ib + 15][e]);
    ushort* dst = Xbf + ((size_t)(e * BT) + bt) * Vdim + i0 + ib;
    *(uint4*)dst = s0;
    *(uint4*)(dst + 8) = s1;
}

// ---------------------------------------------------------------------------
// K1b: Se[e][v][g] (bf16) = srpe[v][g][e] (f32)
// ---------------------------------------------------------------------------
__global__ __launch_bounds__(256) void k_se(const float* __restrict__ srpe,
                                            ushort* __restrict__ Se) {
    __shared__ float t2[256][65];        // [vv*32+g][e], pad 65
    const int tid = threadIdx.x;
    const int v0 = blockIdx.x * 8;
#pragma unroll
    for (int c = 0; c < 16; ++c) {
        int f = (c * 256 + tid) * 4;     // flat f32 idx within block slab
        int vg = f >> 6;
        int e4 = f & 63;
        *(float4*)&t2[vg][e4] = *(const float4*)(srpe + (size_t)v0 * Gdim * Edim + f);
    }
    __syncthreads();
    const int e = tid & 63;
#pragma unroll
    for (int h = 0; h < 2; ++h) {
        const int vv = (tid >> 6) * 2 + h;
        uint4 o[2];
#pragma unroll
        for (int c = 0; c < 2; ++c) {
            o[c].x = pk2(t2[vv * 32 + c * 16 + 0][e],  t2[vv * 32 + c * 16 + 1][e]);
            o[c].y = pk2(t2[vv * 32 + c * 16 + 2][e],  t2[vv * 32 + c * 16 + 3][e]);
            o[c].z = pk2(t2[vv * 32 + c * 16 + 4][e],  t2[vv * 32 + c * 16 + 5][e]);
            o[c].w = pk2(t2[vv * 32 + c * 16 + 6][e],  t2[vv * 32 + c * 16 + 7][e]);
        }
        uint4 o2[2];
#pragma unroll
        for (int c = 0; c < 2; ++c) {
            o2[c].x = pk2(t2[vv * 32 + c * 16 + 8][e],  t2[vv * 32 + c * 16 + 9][e]);
            o2[c].y = pk2(t2[vv * 32 + c * 16 + 10][e], t2[vv * 32 + c * 16 + 11][e]);
            o2[c].z = pk2(t2[vv * 32 + c * 16 + 12][e], t2[vv * 32 + c * 16 + 13][e]);
            o2[c].w = pk2(t2[vv * 32 + c * 16 + 14][e], t2[vv * 32 + c * 16 + 15][e]);
        }
        ushort* dst = Se + ((size_t)(e * Vdim) + v0 + vv) * Gdim;
        *(uint4*)(dst + 0)  = o[0];
        *(uint4*)(dst + 8)  = o2[0];
        *(uint4*)(dst + 16) = o[1];
        *(uint4*)(dst + 24) = o2[1];
    }
}

// ---------------------------------------------------------------------------
// K2: R8-EXACT structure (best known: staged A depth-2, vmcnt(3) discipline).
// PROBE: grid x10 (wgid = blockIdx.x % 1024) to land in rocprof top-5.
// ---------------------------------------------------------------------------
__global__ __launch_bounds__(256, 2) void k_relmix_mfma(const ushort* __restrict__ Xbf,
                                                        const ushort* __restrict__ Se,
                                                        ushort* __restrict__ xrel) {
    __shared__ __align__(16) ushort A_s[3][192 * 32];   // [bt][i], src-swizzled
    __shared__ __align__(16) ushort Si_s[3][32 * 32];   // [i][g],  src-swizzled
    __shared__ __align__(16) ushort R_s[2][128 * 40];   // [v][i],  80 B pitch

    const int tid = threadIdx.x;
    const int l = tid & 63;
    const int w = tid >> 6;              // wave 0..3
    const int wm = w >> 1;               // bt half (96 each)
    const int wn = w & 1;                // v half (64 each)

    const int raw = blockIdx.x % 1024;                // PROBE: 10 passes
    const int wg  = (raw & 7) * 128 + (raw >> 3);     // bijective
    const int e   = wg >> 4;
    const int btT = (wg >> 3) & 1;
    const int vT  = wg & 7;
    const int bt0 = btT * 192;
    const int v0  = vT * 128;

    const int lr  = l >> 2;                           // sub-row in 16-row chunk
    const int lc  = ((l & 3) ^ (lr & 3)) * 8;         // swizzled col (ushort)

    const ushort* gA  = Xbf + ((size_t)(e * BT + bt0)) * Vdim;
    const ushort* gSi = Se + (size_t)e * Vdim * Gdim;

    bf16x8 svF[2];
    {
        const ushort* gSv = Se + ((size_t)e * Vdim + v0) * Gdim;
#pragma unroll
        for (int k = 0; k < 2; ++k) {
            const int vloc = (2 * w + k) * 16 + (l & 15);
            svF[k] = *(const bf16x8*)(gSv + (size_t)vloc * Gdim + (l >> 4) * 8);
        }
    }
    __builtin_amdgcn_sched_barrier(0);

    if (w < 2)
        __builtin_amdgcn_global_load_lds(gSi + (size_t)(0 + w * 16 + lr) * Gdim + lc,
                                         &Si_s[0][w * 512], 16, 0, 0);
#pragma unroll
    for (int c = 0; c < 3; ++c) {
        int chunk = w * 3 + c;
        __builtin_amdgcn_global_load_lds(gA + (size_t)(chunk * 16 + lr) * Vdim + 0 + lc,
                                         &A_s[0][chunk * 512], 16, 0, 0);
    }
    if (w < 2)
        __builtin_amdgcn_global_load_lds(gSi + (size_t)(32 + w * 16 + lr) * Gdim + lc,
                                         &Si_s[1][w * 512], 16, 0, 0);
#pragma unroll
    for (int c = 0; c < 3; ++c) {
        int chunk = w * 3 + c;
        __builtin_amdgcn_global_load_lds(gA + (size_t)(chunk * 16 + lr) * Vdim + 32 + lc,
                                         &A_s[1][chunk * 512], 16, 0, 0);
    }
    asm volatile("s_waitcnt vmcnt(3)" ::: "memory");
    __builtin_amdgcn_sched_barrier(0);
    __builtin_amdgcn_s_barrier();
    __builtin_amdgcn_sched_barrier(0);

    const f32x4 fz = {0.f, 0.f, 0.f, 0.f};

    auto computeR = [&](int sb, int rb) {
        const int r0 = (l & 15), r1 = 16 + (l & 15);
        const int kg = l >> 4;
        bf16x8 siF0 = *(const bf16x8*)&Si_s[sb][r0 * 32 + (kg ^ (r0 & 3)) * 8];
        bf16x8 siF1 = *(const bf16x8*)&Si_s[sb][r1 * 32 + (kg ^ (r1 & 3)) * 8];
#pragma unroll
        for (int k = 0; k < 2; ++k) {
            const int vloc = (2 * w + k) * 16 + (l & 15);
            f32x4 d0 = __builtin_amdgcn_mfma_f32_16x16x32_bf16(siF0, svF[k], fz, 0, 0, 0);
            f32x4 d1 = __builtin_amdgcn_mfma_f32_16x16x32_bf16(siF1, svF[k], fz, 0, 0, 0);
            uint2 w0, w1;
            w0.x = pk2(fmaxf(d0[0], 0.f), fmaxf(d0[1], 0.f));
            w0.y = pk2(fmaxf(d0[2], 0.f), fmaxf(d0[3], 0.f));
            w1.x = pk2(fmaxf(d1[0], 0.f), fmaxf(d1[1], 0.f));
            w1.y = pk2(fmaxf(d1[2], 0.f), fmaxf(d1[3], 0.f));
            *(uint2*)&R_s[rb][vloc * 40 + kg * 4]      = w0;
            *(uint2*)&R_s[rb][vloc * 40 + 16 + kg * 4] = w1;
        }
    };

    computeR(0, 0);
    asm volatile("s_waitcnt lgkmcnt(0)" ::: "memory");
    __builtin_amdgcn_sched_barrier(0);
    __builtin_amdgcn_s_barrier();
    __builtin_amdgcn_sched_barrier(0);

    f32x4 acc[6][4];
#pragma unroll
    for (int m = 0; m < 6; ++m)
#pragma unroll
        for (int n = 0; n < 4; ++n) acc[m][n] = fz;

    int c0 = 0, c1 = 1, c2 = 2;
    int rc = 0, rn = 1;

    for (int t = 0; t < 32; ++t) {
        const int i0f = ((t + 2) & 31) * 32;
        if (w < 2)
            __builtin_amdgcn_global_load_lds(gSi + (size_t)(i0f + w * 16 + lr) * Gdim + lc,
                                             &Si_s[c2][w * 512], 16, 0, 0);
#pragma unroll
        for (int c = 0; c < 3; ++c) {
            int chunk = w * 3 + c;
            __builtin_amdgcn_global_load_lds(gA + (size_t)(chunk * 16 + lr) * Vdim + i0f + lc,
                                             &A_s[c2][chunk * 512], 16, 0, 0);
        }
        computeR(c1, rn);
        bf16x8 aF[6];
#pragma unroll
        for (int m = 0; m < 6; ++m) {
            const int row = wm * 96 + m * 16 + (l & 15);
            aF[m] = *(const bf16x8*)&A_s[c0][row * 32 + (((l >> 4) ^ (row & 3))) * 8];
        }
        __builtin_amdgcn_s_setprio(1);
#pragma unroll
        for (int n = 0; n < 4; ++n) {
            bf16x8 bF = *(const bf16x8*)&R_s[rc][(wn * 64 + n * 16 + (l & 15)) * 40 + (l >> 4) * 8];
#pragma unroll
            for (int m = 0; m < 6; ++m)
                acc[m][n] = __builtin_amdgcn_mfma_f32_16x16x32_bf16(aF[m], bF, acc[m][n], 0, 0, 0);
        }
        __builtin_amdgcn_s_setprio(0);
        asm volatile("s_waitcnt vmcnt(3) lgkmcnt(0)" ::: "memory");
        __builtin_amdgcn_sched_barrier(0);
        __builtin_amdgcn_s_barrier();
        __builtin_amdgcn_sched_barrier(0);
        int tmp = c0; c0 = c1; c1 = c2; c2 = tmp;
        tmp = rc; rc = rn; rn = tmp;
    }

#pragma unroll
    for (int m = 0; m < 6; ++m) {
        const int btl = bt0 + wm * 96 + m * 16 + (l >> 4) * 4;
#pragma unroll
        for (int j = 0; j < 4; ++j) {
            ushort* row = xrel + ((size_t)(e * BT) + btl + j) * Vdim + v0;
#pragma unroll
            for (int n = 0; n < 4; ++n)
                row[wn * 64 + n * 16 + (l & 15)] = f2bf(acc[m][n][j]);
        }
    }
}

// ---------------------------------------------------------------------------
// K2.5: xrT[bt][v][e] = xrel[e][bt][v]   (bf16 -> bf16, XOR-swizzled LDS)
// ---------------------------------------------------------------------------
__global__ __launch_bounds__(256) void k_xrelT(const ushort* __restrict__ xr,
                                               ushort* __restrict__ xrT) {
    __shared__ uint t[64 * 256];         // word (e, vpair), swizzled
    const int tid = threadIdx.x;
    const int bt = blockIdx.x >> 1;
    const int v0 = (blockIdx.x & 1) * 512;
    {
        const int e = tid >> 2, q = tid & 3;
        const ushort* src = xr + ((size_t)(e * BT) + bt) * Vdim + v0 + q * 128;
#pragma unroll
        for (int c = 0; c < 16; ++c) {
            uint4 x = *(const uint4*)(src + c * 8);
            int p = q * 64 + c * 4;
            int sw = ((e & 3) << 3) ^ ((p >> 6) << 2);
            *(uint4*)&t[e * 256 + (p ^ sw)] = x;
        }
    }
    __syncthreads();
    {
        const int p = tid;               // v-pair 0..255
        uint lw[32], hw[32];
#pragma unroll
        for (int e2 = 0; e2 < 32; ++e2) {
            const int ea = 2 * e2, eb = 2 * e2 + 1;
            uint xa = t[ea * 256 + (p ^ (((ea & 3) << 3) ^ ((p >> 6) << 2)))];
            uint xb = t[eb * 256 + (p ^ (((eb & 3) << 3) ^ ((p >> 6) << 2)))];
            lw[e2] = (xa & 0xffffu) | (xb << 16);
            hw[e2] = (xa >> 16) | (xb & 0xffff0000u);
        }
        ushort* d0 = xrT + ((size_t)(bt * Vdim) + v0 + 2 * p) * Edim;
        ushort* d1 = d0 + Edim;
#pragma unroll
        for (int c = 0; c < 8; ++c) {
            uint4 o; o.x = lw[c*4]; o.y = lw[c*4+1]; o.z = lw[c*4+2]; o.w = lw[c*4+3];
            *(uint4*)(d0 + c * 8) = o;
        }
#pragma unroll
        for (int c = 0; c < 8; ++c) {
            uint4 o; o.x = hw[c*4]; o.y = hw[c*4+1]; o.z = hw[c*4+2]; o.w = hw[c*4+3];
            *(uint4*)(d1 + c * 8) = o;
        }
    }
}

// ---------------------------------------------------------------------------
// K3 (R8 structure + nontemporal W/out; measured ~118 us = HBM floor, R11).
// ---------------------------------------------------------------------------
__global__ __launch_bounds__(256, 4) void k_final(const ushort* __restrict__ xrT,
        const int* __restrict__ n_route, const int* __restrict__ s_week,
        const int* __restrict__ s_day,  const float* __restrict__ sape,
        const float* __restrict__ dow,  const float* __restrict__ tod,
        const float* __restrict__ Wc,   const float* __restrict__ bias,
        float* __restrict__ out) {
    __shared__ __align__(16) uint   Wt[2][64 * 36];   // bf16 [e][72f], word units
    __shared__ __align__(16) ushort xs[32 * 216];     // xl bf16 [b][f], pitch 216
    __shared__ float bl[64];
    const int tid = threadIdx.x;
    const int l = tid & 63, w = tid >> 6;
    const int v = blockIdx.x & (Vdim - 1);
    const int t = blockIdx.x >> 10;

    const float* Wg = Wc + ((size_t)(t * Vdim + v)) * 192 * Edim;
    const int i16  = tid & 15;           // e-quad group (cols 4*i16..+3)
    const int j16  = tid >> 4;           // f-quad group (rows 4*j16..+3 in chunk)
    const int colb = i16 * 4;
    const int swW  = (i16 & 3) << 2;     // f-word XOR key, = 4*((e>>2)&3)

    f32x4 wr0[4], wr1[4];
#pragma unroll
    for (int r = 0; r < 4; ++r)
        wr0[r] = __builtin_nontemporal_load((const f32x4*)(Wg + (size_t)(j16 * 4 + r) * Edim + colb));
#pragma unroll
    for (int r = 0; r < 4; ++r)
        wr1[r] = __builtin_nontemporal_load((const f32x4*)(Wg + (size_t)(64 + j16 * 4 + r) * Edim + colb));

    {
        const int b  = tid >> 3;
        const int e0 = (tid & 7) * 8;
        const int bt = b * Tdim + t;
        uint4 raw = *(const uint4*)(xrT + ((size_t)(bt * Vdim) + v) * Edim + e0);
        *(uint4*)&xs[b * 216 + e0] = raw;
        const int r  = n_route[b * Vdim + v];
        const float* sp = sape + ((size_t)(r * Tdim) + t) * Edim + e0;
        const int wd = s_week[bt], dd = s_day[bt];
        const float* dp = dow + ((size_t)(wd * Vdim) + v) * Edim + e0;
        const float* tp = tod + ((size_t)(dd * Vdim) + v) * Edim + e0;
        uint4 o1, o2;
        o1.x = pk2(sp[0], sp[1]); o1.y = pk2(sp[2], sp[3]);
        o1.z = pk2(sp[4], sp[5]); o1.w = pk2(sp[6], sp[7]);
        *(uint4*)&xs[b * 216 + 64 + e0] = o1;
        o2.x = pk2(dp[0] + tp[0], dp[1] + tp[1]);
        o2.y = pk2(dp[2] + tp[2], dp[3] + tp[3]);
        o2.z = pk2(dp[4] + tp[4], dp[5] + tp[5]);
        o2.w = pk2(dp[6] + tp[6], dp[7] + tp[7]);
        *(uint4*)&xs[b * 216 + 128 + e0] = o2;
    }
    if (tid < 64) bl[tid] = bias[((size_t)(t * Vdim) + v) * Edim + tid];

    auto wwrite = [&](int buf, const f32x4* wr) {
#pragma unroll
        for (int k = 0; k < 4; ++k) {
            const int e = colb + k;
            uint2 o;
            o.x = pk2(wr[0][k], wr[1][k]);
            o.y = pk2(wr[2][k], wr[3][k]);
            *(uint2*)&Wt[buf][e * 36 + ((2 * j16) ^ swW)] = o;
        }
    };

    const int mt  = w >> 1;              // b half
    const int ntb = (w & 1) * 2;         // e quarter base
    const f32x4 fz = {0.f, 0.f, 0.f, 0.f};
    f32x4 acc[2] = {fz, fz};
    const int arow = (mt * 16 + (l & 15)) * 216;
    const int g4   = (l >> 4);           // k-group 0..3

    auto computeChunk = [&](int buf, int ksb) {
#pragma unroll
        for (int kk = 0; kk < 2; ++kk) {
            bf16x8 aF = *(const bf16x8*)&xs[arow + (ksb + kk) * 32 + g4 * 8];
#pragma unroll
            for (int ni = 0; ni < 2; ++ni) {
                const int ecol = (ntb + ni) * 16 + (l & 15);
                const int swr  = ((ecol >> 2) & 3) << 2;
                uint4 u = *(const uint4*)&Wt[buf][ecol * 36 + 16 * kk + ((4 * g4) ^ swr)];
                bf16x8 bF;
                __builtin_memcpy(&bF, &u, 16);
                acc[ni] = __builtin_amdgcn_mfma_f32_16x16x32_bf16(aF, bF, acc[ni], 0, 0, 0);
            }
        }
    };

    wwrite(0, wr0);
    __syncthreads();
    f32x4 wr2[4];
#pragma unroll
    for (int r = 0; r < 4; ++r)
        wr2[r] = __builtin_nontemporal_load((const f32x4*)(Wg + (size_t)(128 + j16 * 4 + r) * Edim + colb));
    computeChunk(0, 0);
    wwrite(1, wr1);
    __syncthreads();
    computeChunk(1, 2);
    wwrite(0, wr2);
    __syncthreads();
    computeChunk(0, 4);

    const int brow = mt * 16 + g4 * 4;
#pragma unroll
    for (int ni = 0; ni < 2; ++ni) {
        const int ecol = (ntb + ni) * 16 + (l & 15);
        const float bv = bl[ecol];
#pragma unroll
        for (int j = 0; j < 4; ++j) {
            float s = acc[ni][j] + bv;
            s = s > 0.f ? s : 0.3f * s;
            __builtin_nontemporal_store(s,
                &out[(size_t)(brow + j) * (Tdim * Vdim * Edim)
                     + (size_t)t * (Vdim * Edim) + v * Edim + ecol]);
        }
    }
}

// ---------------------------------------------------------------------------
// PROBE ROUND: k_xpose grid x12, k_relmix_mfma grid x10 (both idempotent)
// so their dispatches exceed the ~350 us harness fills and land in top-5.
// ---------------------------------------------------------------------------
extern "C" void kernel_launch(void* const* d_in, const int* in_sizes, int n_in,
                              void* d_out, int out_size, void* d_ws, size_t ws_size,
                              hipStream_t stream) {
    const float* inputs = (const float*)d_in[0];
    const int*   n_route= (const int*)d_in[1];
    const int*   s_week = (const int*)d_in[2];
    const int*   s_day  = (const int*)d_in[3];
    const float* srpe   = (const float*)d_in[4];
    const float* sape   = (const float*)d_in[5];
    const float* dow    = (const float*)d_in[6];
    const float* tod    = (const float*)d_in[7];
    const float* Wc     = (const float*)d_in[8];
    const float* bias   = (const float*)d_in[9];

    // ws layout: Xbf [0, 48MB) ; Se [48MB, 52MB) ; xrT reuses [0, 48MB) after K2
    ushort* Xbf  = (ushort*)d_ws;
    ushort* Se   = (ushort*)((char*)d_ws + (size_t)Edim * BT * Vdim * 2);
    ushort* xrel = (ushort*)d_out;               // bf16 scratch inside d_out
    ushort* xrT  = (ushort*)d_ws;                // overwrites Xbf (dead after K2)
    float*  out  = (float*)d_out;

    k_xpose<<<dim3(12 * BT * 16), dim3(256), 0, stream>>>(inputs, Xbf);
    k_se<<<dim3(Vdim / 8), dim3(256), 0, stream>>>(srpe, Se);
    k_relmix_mfma<<<dim3(10 * 1024), dim3(256), 0, stream>>>(Xbf, Se, xrel);
    k_xrelT<<<dim3(BT * 2), dim3(256), 0, stream>>>(xrel, xrT);
    k_final<<<dim3(Tdim * Vdim), dim3(256), 0, stream>>>(
        xrT, n_route, s_week, s_day, sape, dow, tod, Wc, bias, out);
}

// Round 14
// 262.056 us; speedup vs baseline: 3.9599x; 3.9599x over previous
//
#include <hip/hip_runtime.h>
#include <stdint.h>

#define Bdim 32
#define Tdim 12
#define Vdim 1024
#define Edim 64
#define Gdim 32
#define BT   384   // B*T

typedef __attribute__((ext_vector_type(8))) short bf16x8;
typedef __attribute__((ext_vector_type(4))) float f32x4;

// pk2(a,b): bf16(a) in low 16, bf16(b) in high 16 — single HW instr, RNE.
__device__ __forceinline__ uint pk2(float a, float b) {
    uint r;
    asm("v_cvt_pk_bf16_f32 %0, %1, %2" : "=v"(r) : "v"(a), "v"(b));
    return r;
}
__device__ __forceinline__ ushort f2bf(float f) {
    return (ushort)(pk2(f, f) & 0xffffu);
}

// ---------------------------------------------------------------------------
// K1a: Xbf[e][bt][i] (bf16) = inputs[bt][i][e] (f32).  ~10 us (measured R13).
// ---------------------------------------------------------------------------
__global__ __launch_bounds__(256) void k_xpose(const float* __restrict__ in,
                                               ushort* __restrict__ Xbf) {
    __shared__ float tile[64][69];
    const int bt = blockIdx.x >> 4;
    const int i0 = (blockIdx.x & 15) << 6;
    const int r  = threadIdx.x >> 2;     // i-local on load, e on store
    const int q  = threadIdx.x & 3;
    const float* src = in + ((size_t)(bt * Vdim) + i0 + r) * Edim + q * 16;
#pragma unroll
    for (int k = 0; k < 4; ++k) {
        float4 x = *(const float4*)(src + 4 * k);
        tile[r][q * 16 + 4 * k + 0] = x.x;
        tile[r][q * 16 + 4 * k + 1] = x.y;
        tile[r][q * 16 + 4 * k + 2] = x.z;
        tile[r][q * 16 + 4 * k + 3] = x.w;
    }
    __syncthreads();
    const int e  = r;
    const int ib = q * 16;
    uint4 s0, s1;
    s0.x = pk2(tile[ib + 0][e],  tile[ib + 1][e]);
    s0.y = pk2(tile[ib + 2][e],  tile[ib + 3][e]);
    s0.z = pk2(tile[ib + 4][e],  tile[ib + 5][e]);
    s0.w = pk2(tile[ib + 6][e],  tile[ib + 7][e]);
    s1.x = pk2(tile[ib + 8][e],  tile[ib + 9][e]);
    s1.y = pk2(tile[ib + 10][e], tile[ib + 11][e]);
    s1.z = pk2(tile[ib + 12][e], tile[ib + 13][e]);
    s1.w = pk2(tile[ib + 14][e], tile[ib + 15][e]);
    ushort* dst = Xbf + ((size_t)(e * BT) + bt) * Vdim + i0 + ib;
    *(uint4*)dst = s0;
    *(uint4*)(dst + 8) = s1;
}

// ---------------------------------------------------------------------------
// K1b: Se[e][v][g] (bf16) = srpe[v][g][e] (f32)
// ---------------------------------------------------------------------------
__global__ __launch_bounds__(256) void k_se(const float* __restrict__ srpe,
                                            ushort* __restrict__ Se) {
    __shared__ float t2[256][65];        // [vv*32+g][e], pad 65
    const int tid = threadIdx.x;
    const int v0 = blockIdx.x * 8;
#pragma unroll
    for (int c = 0; c < 16; ++c) {
        int f = (c * 256 + tid) * 4;     // flat f32 idx within block slab
        int vg = f >> 6;
        int e4 = f & 63;
        *(float4*)&t2[vg][e4] = *(const float4*)(srpe + (size_t)v0 * Gdim * Edim + f);
    }
    __syncthreads();
    const int e = tid & 63;
#pragma unroll
    for (int h = 0; h < 2; ++h) {
        const int vv = (tid >> 6) * 2 + h;
        uint4 o[2];
#pragma unroll
        for (int c = 0; c < 2; ++c) {
            o[c].x = pk2(t2[vv * 32 + c * 16 + 0][e],  t2[vv * 32 + c * 16 + 1][e]);
            o[c].y = pk2(t2[vv * 32 + c * 16 + 2][e],  t2[vv * 32 + c * 16 + 3][e]);
            o[c].z = pk2(t2[vv * 32 + c * 16 + 4][e],  t2[vv * 32 + c * 16 + 5][e]);
            o[c].w = pk2(t2[vv * 32 + c * 16 + 6][e],  t2[vv * 32 + c * 16 + 7][e]);
        }
        uint4 o2[2];
#pragma unroll
        for (int c = 0; c < 2; ++c) {
            o2[c].x = pk2(t2[vv * 32 + c * 16 + 8][e],  t2[vv * 32 + c * 16 + 9][e]);
            o2[c].y = pk2(t2[vv * 32 + c * 16 + 10][e], t2[vv * 32 + c * 16 + 11][e]);
            o2[c].z = pk2(t2[vv * 32 + c * 16 + 12][e], t2[vv * 32 + c * 16 + 13][e]);
            o2[c].w = pk2(t2[vv * 32 + c * 16 + 14][e], t2[vv * 32 + c * 16 + 15][e]);
        }
        ushort* dst = Se + ((size_t)(e * Vdim) + v0 + vv) * Gdim;
        *(uint4*)(dst + 0)  = o[0];
        *(uint4*)(dst + 8)  = o2[0];
        *(uint4*)(dst + 16) = o[1];
        *(uint4*)(dst + 24) = o2[1];
    }
}

// ---------------------------------------------------------------------------
// K2: R8-EXACT (measured 68.5 us, MfmaUtil 39%).  Unchanged this round.
// ---------------------------------------------------------------------------
__global__ __launch_bounds__(256, 2) void k_relmix_mfma(const ushort* __restrict__ Xbf,
                                                        const ushort* __restrict__ Se,
                                                        ushort* __restrict__ xrel) {
    __shared__ __align__(16) ushort A_s[3][192 * 32];   // [bt][i], src-swizzled
    __shared__ __align__(16) ushort Si_s[3][32 * 32];   // [i][g],  src-swizzled
    __shared__ __align__(16) ushort R_s[2][128 * 40];   // [v][i],  80 B pitch

    const int tid = threadIdx.x;
    const int l = tid & 63;
    const int w = tid >> 6;              // wave 0..3
    const int wm = w >> 1;               // bt half (96 each)
    const int wn = w & 1;                // v half (64 each)

    const int raw = blockIdx.x;                       // 0..1023
    const int wg  = (raw & 7) * 128 + (raw >> 3);     // bijective
    const int e   = wg >> 4;
    const int btT = (wg >> 3) & 1;
    const int vT  = wg & 7;
    const int bt0 = btT * 192;
    const int v0  = vT * 128;

    const int lr  = l >> 2;                           // sub-row in 16-row chunk
    const int lc  = ((l & 3) ^ (lr & 3)) * 8;         // swizzled col (ushort)

    const ushort* gA  = Xbf + ((size_t)(e * BT + bt0)) * Vdim;
    const ushort* gSi = Se + (size_t)e * Vdim * Gdim;

    bf16x8 svF[2];
    {
        const ushort* gSv = Se + ((size_t)e * Vdim + v0) * Gdim;
#pragma unroll
        for (int k = 0; k < 2; ++k) {
            const int vloc = (2 * w + k) * 16 + (l & 15);
            svF[k] = *(const bf16x8*)(gSv + (size_t)vloc * Gdim + (l >> 4) * 8);
        }
    }
    __builtin_amdgcn_sched_barrier(0);

    if (w < 2)
        __builtin_amdgcn_global_load_lds(gSi + (size_t)(0 + w * 16 + lr) * Gdim + lc,
                                         &Si_s[0][w * 512], 16, 0, 0);
#pragma unroll
    for (int c = 0; c < 3; ++c) {
        int chunk = w * 3 + c;
        __builtin_amdgcn_global_load_lds(gA + (size_t)(chunk * 16 + lr) * Vdim + 0 + lc,
                                         &A_s[0][chunk * 512], 16, 0, 0);
    }
    if (w < 2)
        __builtin_amdgcn_global_load_lds(gSi + (size_t)(32 + w * 16 + lr) * Gdim + lc,
                                         &Si_s[1][w * 512], 16, 0, 0);
#pragma unroll
    for (int c = 0; c < 3; ++c) {
        int chunk = w * 3 + c;
        __builtin_amdgcn_global_load_lds(gA + (size_t)(chunk * 16 + lr) * Vdim + 32 + lc,
                                         &A_s[1][chunk * 512], 16, 0, 0);
    }
    asm volatile("s_waitcnt vmcnt(3)" ::: "memory");
    __builtin_amdgcn_sched_barrier(0);
    __builtin_amdgcn_s_barrier();
    __builtin_amdgcn_sched_barrier(0);

    const f32x4 fz = {0.f, 0.f, 0.f, 0.f};

    auto computeR = [&](int sb, int rb) {
        const int r0 = (l & 15), r1 = 16 + (l & 15);
        const int kg = l >> 4;
        bf16x8 siF0 = *(const bf16x8*)&Si_s[sb][r0 * 32 + (kg ^ (r0 & 3)) * 8];
        bf16x8 siF1 = *(const bf16x8*)&Si_s[sb][r1 * 32 + (kg ^ (r1 & 3)) * 8];
#pragma unroll
        for (int k = 0; k < 2; ++k) {
            const int vloc = (2 * w + k) * 16 + (l & 15);
            f32x4 d0 = __builtin_amdgcn_mfma_f32_16x16x32_bf16(siF0, svF[k], fz, 0, 0, 0);
            f32x4 d1 = __builtin_amdgcn_mfma_f32_16x16x32_bf16(siF1, svF[k], fz, 0, 0, 0);
            uint2 w0, w1;
            w0.x = pk2(fmaxf(d0[0], 0.f), fmaxf(d0[1], 0.f));
            w0.y = pk2(fmaxf(d0[2], 0.f), fmaxf(d0[3], 0.f));
            w1.x = pk2(fmaxf(d1[0], 0.f), fmaxf(d1[1], 0.f));
            w1.y = pk2(fmaxf(d1[2], 0.f), fmaxf(d1[3], 0.f));
            *(uint2*)&R_s[rb][vloc * 40 + kg * 4]      = w0;
            *(uint2*)&R_s[rb][vloc * 40 + 16 + kg * 4] = w1;
        }
    };

    computeR(0, 0);
    asm volatile("s_waitcnt lgkmcnt(0)" ::: "memory");
    __builtin_amdgcn_sched_barrier(0);
    __builtin_amdgcn_s_barrier();
    __builtin_amdgcn_sched_barrier(0);

    f32x4 acc[6][4];
#pragma unroll
    for (int m = 0; m < 6; ++m)
#pragma unroll
        for (int n = 0; n < 4; ++n) acc[m][n] = fz;

    int c0 = 0, c1 = 1, c2 = 2;
    int rc = 0, rn = 1;

    for (int t = 0; t < 32; ++t) {
        const int i0f = ((t + 2) & 31) * 32;
        if (w < 2)
            __builtin_amdgcn_global_load_lds(gSi + (size_t)(i0f + w * 16 + lr) * Gdim + lc,
                                             &Si_s[c2][w * 512], 16, 0, 0);
#pragma unroll
        for (int c = 0; c < 3; ++c) {
            int chunk = w * 3 + c;
            __builtin_amdgcn_global_load_lds(gA + (size_t)(chunk * 16 + lr) * Vdim + i0f + lc,
                                             &A_s[c2][chunk * 512], 16, 0, 0);
        }
        computeR(c1, rn);
        bf16x8 aF[6];
#pragma unroll
        for (int m = 0; m < 6; ++m) {
            const int row = wm * 96 + m * 16 + (l & 15);
            aF[m] = *(const bf16x8*)&A_s[c0][row * 32 + (((l >> 4) ^ (row & 3))) * 8];
        }
        __builtin_amdgcn_s_setprio(1);
#pragma unroll
        for (int n = 0; n < 4; ++n) {
            bf16x8 bF = *(const bf16x8*)&R_s[rc][(wn * 64 + n * 16 + (l & 15)) * 40 + (l >> 4) * 8];
#pragma unroll
            for (int m = 0; m < 6; ++m)
                acc[m][n] = __builtin_amdgcn_mfma_f32_16x16x32_bf16(aF[m], bF, acc[m][n], 0, 0, 0);
        }
        __builtin_amdgcn_s_setprio(0);
        asm volatile("s_waitcnt vmcnt(3) lgkmcnt(0)" ::: "memory");
        __builtin_amdgcn_sched_barrier(0);
        __builtin_amdgcn_s_barrier();
        __builtin_amdgcn_sched_barrier(0);
        int tmp = c0; c0 = c1; c1 = c2; c2 = tmp;
        tmp = rc; rc = rn; rn = tmp;
    }

#pragma unroll
    for (int m = 0; m < 6; ++m) {
        const int btl = bt0 + wm * 96 + m * 16 + (l >> 4) * 4;
#pragma unroll
        for (int j = 0; j < 4; ++j) {
            ushort* row = xrel + ((size_t)(e * BT) + btl + j) * Vdim + v0;
#pragma unroll
            for (int n = 0; n < 4; ++n)
                row[wn * 64 + n * 16 + (l & 15)] = f2bf(acc[m][n][j]);
        }
    }
}

// ---------------------------------------------------------------------------
// K2.5 v2: xrT[bt][v][e] = xrel[e][bt][v].  FULLY COALESCED both sides:
// - load: wave w, iter i -> e=w*16+i; 64 lanes read contiguous 1 KB.
// - LDS: word(e,p) at index p ^ key(e), key = ((e&7)^((e>>3)&7))<<2
//   (covers both e&7 and e>>3 so load AND readback are conflict-free).
// - store: 8 lanes fill each 128-B line; 8 full lines per instr (optimal);
//   per-wg output is one contiguous 64 KB run.
// ---------------------------------------------------------------------------
__global__ __launch_bounds__(256) void k_xrelT(const ushort* __restrict__ xr,
                                               ushort* __restrict__ xrT) {
    __shared__ uint t[64 * 256];         // word (e, v-pair), swizzled
    const int tid = threadIdx.x;
    const int l = tid & 63, w = tid >> 6;
    const int bt = blockIdx.x >> 1;
    const int v0 = (blockIdx.x & 1) * 512;

#pragma unroll
    for (int i = 0; i < 16; ++i) {
        const int e = w * 16 + i;
        const int key = ((e & 7) ^ ((e >> 3) & 7)) << 2;
        uint4 x = *(const uint4*)(xr + ((size_t)(e * BT) + bt) * Vdim + v0 + l * 8);
        *(uint4*)&t[e * 256 + ((l * 4) ^ key)] = x;
    }
    __syncthreads();

    ushort* dst = xrT + ((size_t)bt * Vdim + v0) * Edim;   // contiguous 64 KB
#pragma unroll
    for (int j = 0; j < 8; ++j) {
        const int q = tid + 256 * j;
        const int p = q >> 3;            // v-pair 0..255
        const int k = q & 7;             // e-octet 0..7
        uint lo[4], hi[4];
#pragma unroll
        for (int c = 0; c < 4; ++c) {
            const int ea = 8 * k + 2 * c;
            const int eb = ea + 1;
            const uint A = t[ea * 256 + (p ^ (((ea & 7) ^ ((ea >> 3) & 7)) << 2))];
            const uint B = t[eb * 256 + (p ^ (((eb & 7) ^ ((eb >> 3) & 7)) << 2))];
            lo[c] = (A & 0xffffu) | (B << 16);
            hi[c] = (A >> 16) | (B & 0xffff0000u);
        }
        uint4 o0, o1;
        o0.x = lo[0]; o0.y = lo[1]; o0.z = lo[2]; o0.w = lo[3];
        o1.x = hi[0]; o1.y = hi[1]; o1.z = hi[2]; o1.w = hi[3];
        *(uint4*)(dst + (size_t)((2 * p) * 8 + k) * 8)     = o0;
        *(uint4*)(dst + (size_t)((2 * p + 1) * 8 + k) * 8) = o1;
    }
}

// ---------------------------------------------------------------------------
// K3 (R8 structure + nontemporal W/out; ~120 us = HBM floor, measured R11).
// ---------------------------------------------------------------------------
__global__ __launch_bounds__(256, 4) void k_final(const ushort* __restrict__ xrT,
        const int* __restrict__ n_route, const int* __restrict__ s_week,
        const int* __restrict__ s_day,  const float* __restrict__ sape,
        const float* __restrict__ dow,  const float* __restrict__ tod,
        const float* __restrict__ Wc,   const float* __restrict__ bias,
        float* __restrict__ out) {
    __shared__ __align__(16) uint   Wt[2][64 * 36];   // bf16 [e][72f], word units
    __shared__ __align__(16) ushort xs[32 * 216];     // xl bf16 [b][f], pitch 216
    __shared__ float bl[64];
    const int tid = threadIdx.x;
    const int l = tid & 63, w = tid >> 6;
    const int v = blockIdx.x & (Vdim - 1);
    const int t = blockIdx.x >> 10;

    const float* Wg = Wc + ((size_t)(t * Vdim + v)) * 192 * Edim;
    const int i16  = tid & 15;           // e-quad group (cols 4*i16..+3)
    const int j16  = tid >> 4;           // f-quad group (rows 4*j16..+3 in chunk)
    const int colb = i16 * 4;
    const int swW  = (i16 & 3) << 2;     // f-word XOR key, = 4*((e>>2)&3)

    f32x4 wr0[4], wr1[4];
#pragma unroll
    for (int r = 0; r < 4; ++r)
        wr0[r] = __builtin_nontemporal_load((const f32x4*)(Wg + (size_t)(j16 * 4 + r) * Edim + colb));
#pragma unroll
    for (int r = 0; r < 4; ++r)
        wr1[r] = __builtin_nontemporal_load((const f32x4*)(Wg + (size_t)(64 + j16 * 4 + r) * Edim + colb));

    {
        const int b  = tid >> 3;
        const int e0 = (tid & 7) * 8;
        const int bt = b * Tdim + t;
        uint4 raw = *(const uint4*)(xrT + ((size_t)(bt * Vdim) + v) * Edim + e0);
        *(uint4*)&xs[b * 216 + e0] = raw;
        const int r  = n_route[b * Vdim + v];
        const float* sp = sape + ((size_t)(r * Tdim) + t) * Edim + e0;
        const int wd = s_week[bt], dd = s_day[bt];
        const float* dp = dow + ((size_t)(wd * Vdim) + v) * Edim + e0;
        const float* tp = tod + ((size_t)(dd * Vdim) + v) * Edim + e0;
        uint4 o1, o2;
        o1.x = pk2(sp[0], sp[1]); o1.y = pk2(sp[2], sp[3]);
        o1.z = pk2(sp[4], sp[5]); o1.w = pk2(sp[6], sp[7]);
        *(uint4*)&xs[b * 216 + 64 + e0] = o1;
        o2.x = pk2(dp[0] + tp[0], dp[1] + tp[1]);
        o2.y = pk2(dp[2] + tp[2], dp[3] + tp[3]);
        o2.z = pk2(dp[4] + tp[4], dp[5] + tp[5]);
        o2.w = pk2(dp[6] + tp[6], dp[7] + tp[7]);
        *(uint4*)&xs[b * 216 + 128 + e0] = o2;
    }
    if (tid < 64) bl[tid] = bias[((size_t)(t * Vdim) + v) * Edim + tid];

    auto wwrite = [&](int buf, const f32x4* wr) {
#pragma unroll
        for (int k = 0; k < 4; ++k) {
            const int e = colb + k;
            uint2 o;
            o.x = pk2(wr[0][k], wr[1][k]);
            o.y = pk2(wr[2][k], wr[3][k]);
            *(uint2*)&Wt[buf][e * 36 + ((2 * j16) ^ swW)] = o;
        }
    };

    const int mt  = w >> 1;              // b half
    const int ntb = (w & 1) * 2;         // e quarter base
    const f32x4 fz = {0.f, 0.f, 0.f, 0.f};
    f32x4 acc[2] = {fz, fz};
    const int arow = (mt * 16 + (l & 15)) * 216;
    const int g4   = (l >> 4);           // k-group 0..3

    auto computeChunk = [&](int buf, int ksb) {
#pragma unroll
        for (int kk = 0; kk < 2; ++kk) {
            bf16x8 aF = *(const bf16x8*)&xs[arow + (ksb + kk) * 32 + g4 * 8];
#pragma unroll
            for (int ni = 0; ni < 2; ++ni) {
                const int ecol = (ntb + ni) * 16 + (l & 15);
                const int swr  = ((ecol >> 2) & 3) << 2;
                uint4 u = *(const uint4*)&Wt[buf][ecol * 36 + 16 * kk + ((4 * g4) ^ swr)];
                bf16x8 bF;
                __builtin_memcpy(&bF, &u, 16);
                acc[ni] = __builtin_amdgcn_mfma_f32_16x16x32_bf16(aF, bF, acc[ni], 0, 0, 0);
            }
        }
    };

    wwrite(0, wr0);
    __syncthreads();
    f32x4 wr2[4];
#pragma unroll
    for (int r = 0; r < 4; ++r)
        wr2[r] = __builtin_nontemporal_load((const f32x4*)(Wg + (size_t)(128 + j16 * 4 + r) * Edim + colb));
    computeChunk(0, 0);
    wwrite(1, wr1);
    __syncthreads();
    computeChunk(1, 2);
    wwrite(0, wr2);
    __syncthreads();
    computeChunk(0, 4);

    const int brow = mt * 16 + g4 * 4;
#pragma unroll
    for (int ni = 0; ni < 2; ++ni) {
        const int ecol = (ntb + ni) * 16 + (l & 15);
        const float bv = bl[ecol];
#pragma unroll
        for (int j = 0; j < 4; ++j) {
            float s = acc[ni][j] + bv;
            s = s > 0.f ? s : 0.3f * s;
            __builtin_nontemporal_store(s,
                &out[(size_t)(brow + j) * (Tdim * Vdim * Edim)
                     + (size_t)t * (Vdim * Edim) + v * Edim + ecol]);
        }
    }
}

// ---------------------------------------------------------------------------
extern "C" void kernel_launch(void* const* d_in, const int* in_sizes, int n_in,
                              void* d_out, int out_size, void* d_ws, size_t ws_size,
                              hipStream_t stream) {
    const float* inputs = (const float*)d_in[0];
    const int*   n_route= (const int*)d_in[1];
    const int*   s_week = (const int*)d_in[2];
    const int*   s_day  = (const int*)d_in[3];
    const float* srpe   = (const float*)d_in[4];
    const float* sape   = (const float*)d_in[5];
    const float* dow    = (const float*)d_in[6];
    const float* tod    = (const float*)d_in[7];
    const float* Wc     = (const float*)d_in[8];
    const float* bias   = (const float*)d_in[9];

    // ws layout: Xbf [0, 48MB) ; Se [48MB, 52MB) ; xrT reuses [0, 48MB) after K2
    ushort* Xbf  = (ushort*)d_ws;
    ushort* Se   = (ushort*)((char*)d_ws + (size_t)Edim * BT * Vdim * 2);
    ushort* xrel = (ushort*)d_out;               // bf16 scratch inside d_out
    ushort* xrT  = (ushort*)d_ws;                // overwrites Xbf (dead after K2)
    float*  out  = (float*)d_out;

    k_xpose<<<dim3(BT * 16), dim3(256), 0, stream>>>(inputs, Xbf);
    k_se<<<dim3(Vdim / 8), dim3(256), 0, stream>>>(srpe, Se);
    k_relmix_mfma<<<dim3(1024), dim3(256), 0, stream>>>(Xbf, Se, xrel);
    k_xrelT<<<dim3(BT * 2), dim3(256), 0, stream>>>(xrel, xrT);
    k_final<<<dim3(Tdim * Vdim), dim3(256), 0, stream>>>(
        xrT, n_route, s_week, s_day, sape, dow, tod, Wc, bias, out);
}

// Round 15
// 258.988 us; speedup vs baseline: 4.0068x; 1.0118x over previous
//
#include <hip/hip_runtime.h>
#include <stdint.h>

#define Bdim 32
#define Tdim 12
#define Vdim 1024
#define Edim 64
#define Gdim 32
#define BT   384   // B*T

typedef __attribute__((ext_vector_type(8))) short bf16x8;
typedef __attribute__((ext_vector_type(4))) float f32x4;

// pk2(a,b): bf16(a) in low 16, bf16(b) in high 16 — single HW instr, RNE.
__device__ __forceinline__ uint pk2(float a, float b) {
    uint r;
    asm("v_cvt_pk_bf16_f32 %0, %1, %2" : "=v"(r) : "v"(a), "v"(b));
    return r;
}
__device__ __forceinline__ ushort f2bf(float f) {
    return (ushort)(pk2(f, f) & 0xffffu);
}

// ---------------------------------------------------------------------------
// K1a: Xbf[e][bt][i] (bf16) = inputs[bt][i][e] (f32).  ~10 us (measured R13).
// ---------------------------------------------------------------------------
__global__ __launch_bounds__(256) void k_xpose(const float* __restrict__ in,
                                               ushort* __restrict__ Xbf) {
    __shared__ float tile[64][69];
    const int bt = blockIdx.x >> 4;
    const int i0 = (blockIdx.x & 15) << 6;
    const int r  = threadIdx.x >> 2;     // i-local on load, e on store
    const int q  = threadIdx.x & 3;
    const float* src = in + ((size_t)(bt * Vdim) + i0 + r) * Edim + q * 16;
#pragma unroll
    for (int k = 0; k < 4; ++k) {
        float4 x = *(const float4*)(src + 4 * k);
        tile[r][q * 16 + 4 * k + 0] = x.x;
        tile[r][q * 16 + 4 * k + 1] = x.y;
        tile[r][q * 16 + 4 * k + 2] = x.z;
        tile[r][q * 16 + 4 * k + 3] = x.w;
    }
    __syncthreads();
    const int e  = r;
    const int ib = q * 16;
    uint4 s0, s1;
    s0.x = pk2(tile[ib + 0][e],  tile[ib + 1][e]);
    s0.y = pk2(tile[ib + 2][e],  tile[ib + 3][e]);
    s0.z = pk2(tile[ib + 4][e],  tile[ib + 5][e]);
    s0.w = pk2(tile[ib + 6][e],  tile[ib + 7][e]);
    s1.x = pk2(tile[ib + 8][e],  tile[ib + 9][e]);
    s1.y = pk2(tile[ib + 10][e], tile[ib + 11][e]);
    s1.z = pk2(tile[ib + 12][e], tile[ib + 13][e]);
    s1.w = pk2(tile[ib + 14][e], tile[ib + 15][e]);
    ushort* dst = Xbf + ((size_t)(e * BT) + bt) * Vdim + i0 + ib;
    *(uint4*)dst = s0;
    *(uint4*)(dst + 8) = s1;
}

// ---------------------------------------------------------------------------
// K1b: Se[e][v][g] (bf16) = srpe[v][g][e] (f32)
// ---------------------------------------------------------------------------
__global__ __launch_bounds__(256) void k_se(const float* __restrict__ srpe,
                                            ushort* __restrict__ Se) {
    __shared__ float t2[256][65];        // [vv*32+g][e], pad 65
    const int tid = threadIdx.x;
    const int v0 = blockIdx.x * 8;
#pragma unroll
    for (int c = 0; c < 16; ++c) {
        int f = (c * 256 + tid) * 4;     // flat f32 idx within block slab
        int vg = f >> 6;
        int e4 = f & 63;
        *(float4*)&t2[vg][e4] = *(const float4*)(srpe + (size_t)v0 * Gdim * Edim + f);
    }
    __syncthreads();
    const int e = tid & 63;
#pragma unroll
    for (int h = 0; h < 2; ++h) {
        const int vv = (tid >> 6) * 2 + h;
        uint4 o[2];
#pragma unroll
        for (int c = 0; c < 2; ++c) {
            o[c].x = pk2(t2[vv * 32 + c * 16 + 0][e],  t2[vv * 32 + c * 16 + 1][e]);
            o[c].y = pk2(t2[vv * 32 + c * 16 + 2][e],  t2[vv * 32 + c * 16 + 3][e]);
            o[c].z = pk2(t2[vv * 32 + c * 16 + 4][e],  t2[vv * 32 + c * 16 + 5][e]);
            o[c].w = pk2(t2[vv * 32 + c * 16 + 6][e],  t2[vv * 32 + c * 16 + 7][e]);
        }
        uint4 o2[2];
#pragma unroll
        for (int c = 0; c < 2; ++c) {
            o2[c].x = pk2(t2[vv * 32 + c * 16 + 8][e],  t2[vv * 32 + c * 16 + 9][e]);
            o2[c].y = pk2(t2[vv * 32 + c * 16 + 10][e], t2[vv * 32 + c * 16 + 11][e]);
            o2[c].z = pk2(t2[vv * 32 + c * 16 + 12][e], t2[vv * 32 + c * 16 + 13][e]);
            o2[c].w = pk2(t2[vv * 32 + c * 16 + 14][e], t2[vv * 32 + c * 16 + 15][e]);
        }
        ushort* dst = Se + ((size_t)(e * Vdim) + v0 + vv) * Gdim;
        *(uint4*)(dst + 0)  = o[0];
        *(uint4*)(dst + 8)  = o2[0];
        *(uint4*)(dst + 16) = o[1];
        *(uint4*)(dst + 24) = o2[1];
    }
}

// ---------------------------------------------------------------------------
// K2: R8 structure + FULL XOR swizzle (r&3)^((r>>2)&3) on stage/aF/siF —
// aF reads go 4-way -> 2-way (free).  Measured base: 68.5 us, 39% MfmaUtil.
// ---------------------------------------------------------------------------
__global__ __launch_bounds__(256, 2) void k_relmix_mfma(const ushort* __restrict__ Xbf,
                                                        const ushort* __restrict__ Se,
                                                        ushort* __restrict__ xrel) {
    __shared__ __align__(16) ushort A_s[3][192 * 32];   // [bt][i], src-swizzled
    __shared__ __align__(16) ushort Si_s[3][32 * 32];   // [i][g],  src-swizzled
    __shared__ __align__(16) ushort R_s[2][128 * 40];   // [v][i],  80 B pitch

    const int tid = threadIdx.x;
    const int l = tid & 63;
    const int w = tid >> 6;              // wave 0..3
    const int wm = w >> 1;               // bt half (96 each)
    const int wn = w & 1;                // v half (64 each)

    const int raw = blockIdx.x;                       // 0..1023
    const int wg  = (raw & 7) * 128 + (raw >> 3);     // bijective
    const int e   = wg >> 4;
    const int btT = (wg >> 3) & 1;
    const int vT  = wg & 7;
    const int bt0 = btT * 192;
    const int v0  = vT * 128;

    const int lr  = l >> 2;                           // sub-row in 16-row chunk
    const int lc  = ((l & 3) ^ (lr & 3) ^ ((lr >> 2) & 3)) * 8;  // FULL swizzle

    const ushort* gA  = Xbf + ((size_t)(e * BT + bt0)) * Vdim;
    const ushort* gSi = Se + (size_t)e * Vdim * Gdim;

    bf16x8 svF[2];
    {
        const ushort* gSv = Se + ((size_t)e * Vdim + v0) * Gdim;
#pragma unroll
        for (int k = 0; k < 2; ++k) {
            const int vloc = (2 * w + k) * 16 + (l & 15);
            svF[k] = *(const bf16x8*)(gSv + (size_t)vloc * Gdim + (l >> 4) * 8);
        }
    }
    __builtin_amdgcn_sched_barrier(0);

    if (w < 2)
        __builtin_amdgcn_global_load_lds(gSi + (size_t)(0 + w * 16 + lr) * Gdim + lc,
                                         &Si_s[0][w * 512], 16, 0, 0);
#pragma unroll
    for (int c = 0; c < 3; ++c) {
        int chunk = w * 3 + c;
        __builtin_amdgcn_global_load_lds(gA + (size_t)(chunk * 16 + lr) * Vdim + 0 + lc,
                                         &A_s[0][chunk * 512], 16, 0, 0);
    }
    if (w < 2)
        __builtin_amdgcn_global_load_lds(gSi + (size_t)(32 + w * 16 + lr) * Gdim + lc,
                                         &Si_s[1][w * 512], 16, 0, 0);
#pragma unroll
    for (int c = 0; c < 3; ++c) {
        int chunk = w * 3 + c;
        __builtin_amdgcn_global_load_lds(gA + (size_t)(chunk * 16 + lr) * Vdim + 32 + lc,
                                         &A_s[1][chunk * 512], 16, 0, 0);
    }
    asm volatile("s_waitcnt vmcnt(3)" ::: "memory");
    __builtin_amdgcn_sched_barrier(0);
    __builtin_amdgcn_s_barrier();
    __builtin_amdgcn_sched_barrier(0);

    const f32x4 fz = {0.f, 0.f, 0.f, 0.f};

    auto computeR = [&](int sb, int rb) {
        const int r0 = (l & 15), r1 = 16 + (l & 15);
        const int kg = l >> 4;
        const int k0 = (kg ^ (r0 & 3) ^ ((r0 >> 2) & 3)) * 8;   // r1 shares key
        bf16x8 siF0 = *(const bf16x8*)&Si_s[sb][r0 * 32 + k0];
        bf16x8 siF1 = *(const bf16x8*)&Si_s[sb][r1 * 32 + k0];
#pragma unroll
        for (int k = 0; k < 2; ++k) {
            const int vloc = (2 * w + k) * 16 + (l & 15);
            f32x4 d0 = __builtin_amdgcn_mfma_f32_16x16x32_bf16(siF0, svF[k], fz, 0, 0, 0);
            f32x4 d1 = __builtin_amdgcn_mfma_f32_16x16x32_bf16(siF1, svF[k], fz, 0, 0, 0);
            uint2 w0, w1;
            w0.x = pk2(fmaxf(d0[0], 0.f), fmaxf(d0[1], 0.f));
            w0.y = pk2(fmaxf(d0[2], 0.f), fmaxf(d0[3], 0.f));
            w1.x = pk2(fmaxf(d1[0], 0.f), fmaxf(d1[1], 0.f));
            w1.y = pk2(fmaxf(d1[2], 0.f), fmaxf(d1[3], 0.f));
            *(uint2*)&R_s[rb][vloc * 40 + kg * 4]      = w0;
            *(uint2*)&R_s[rb][vloc * 40 + 16 + kg * 4] = w1;
        }
    };

    computeR(0, 0);
    asm volatile("s_waitcnt lgkmcnt(0)" ::: "memory");
    __builtin_amdgcn_sched_barrier(0);
    __builtin_amdgcn_s_barrier();
    __builtin_amdgcn_sched_barrier(0);

    f32x4 acc[6][4];
#pragma unroll
    for (int m = 0; m < 6; ++m)
#pragma unroll
        for (int n = 0; n < 4; ++n) acc[m][n] = fz;

    int c0 = 0, c1 = 1, c2 = 2;
    int rc = 0, rn = 1;

    for (int t = 0; t < 32; ++t) {
        const int i0f = ((t + 2) & 31) * 32;
        if (w < 2)
            __builtin_amdgcn_global_load_lds(gSi + (size_t)(i0f + w * 16 + lr) * Gdim + lc,
                                             &Si_s[c2][w * 512], 16, 0, 0);
#pragma unroll
        for (int c = 0; c < 3; ++c) {
            int chunk = w * 3 + c;
            __builtin_amdgcn_global_load_lds(gA + (size_t)(chunk * 16 + lr) * Vdim + i0f + lc,
                                             &A_s[c2][chunk * 512], 16, 0, 0);
        }
        computeR(c1, rn);
        bf16x8 aF[6];
#pragma unroll
        for (int m = 0; m < 6; ++m) {
            const int row = wm * 96 + m * 16 + (l & 15);
            const int key = ((l >> 4) ^ (row & 3) ^ ((row >> 2) & 3)) * 8;
            aF[m] = *(const bf16x8*)&A_s[c0][row * 32 + key];
        }
        __builtin_amdgcn_s_setprio(1);
#pragma unroll
        for (int n = 0; n < 4; ++n) {
            bf16x8 bF = *(const bf16x8*)&R_s[rc][(wn * 64 + n * 16 + (l & 15)) * 40 + (l >> 4) * 8];
#pragma unroll
            for (int m = 0; m < 6; ++m)
                acc[m][n] = __builtin_amdgcn_mfma_f32_16x16x32_bf16(aF[m], bF, acc[m][n], 0, 0, 0);
        }
        __builtin_amdgcn_s_setprio(0);
        asm volatile("s_waitcnt vmcnt(3) lgkmcnt(0)" ::: "memory");
        __builtin_amdgcn_sched_barrier(0);
        __builtin_amdgcn_s_barrier();
        __builtin_amdgcn_sched_barrier(0);
        int tmp = c0; c0 = c1; c1 = c2; c2 = tmp;
        tmp = rc; rc = rn; rn = tmp;
    }

#pragma unroll
    for (int m = 0; m < 6; ++m) {
        const int btl = bt0 + wm * 96 + m * 16 + (l >> 4) * 4;
#pragma unroll
        for (int j = 0; j < 4; ++j) {
            ushort* row = xrel + ((size_t)(e * BT) + btl + j) * Vdim + v0;
#pragma unroll
            for (int n = 0; n < 4; ++n)
                row[wn * 64 + n * 16 + (l & 15)] = f2bf(acc[m][n][j]);
        }
    }
}

// ---------------------------------------------------------------------------
// K2.5 v3: xrT[bt][v][e] = xrel[e][bt][v].  32 KB LDS (4-5 wg/CU), 1536 wgs.
// Per wg: 64 e x 256 v.  Loads: 2 e-rows x 512 B per instr (coalesced).
// Readback: 8 full 128-B lines per store instr.  Banks 2-way max (verified).
// ---------------------------------------------------------------------------
__global__ __launch_bounds__(256) void k_xrelT(const ushort* __restrict__ xr,
                                               ushort* __restrict__ xrT) {
    __shared__ uint t[64 * 128];         // word (e, v-pair local), swizzled
    const int tid = threadIdx.x;
    const int l = tid & 63, w = tid >> 6;
    const int bt = blockIdx.x >> 2;
    const int v0 = (blockIdx.x & 3) * 256;

#pragma unroll
    for (int i = 0; i < 8; ++i) {
        const int e = w * 16 + 2 * i + (l >> 5);
        const int key = ((e & 7) ^ ((e >> 3) & 7)) << 2;
        uint4 x = *(const uint4*)(xr + ((size_t)(e * BT) + bt) * Vdim + v0 + (l & 31) * 8);
        *(uint4*)&t[e * 128 + ((((l & 31) * 4)) ^ key)] = x;
    }
    __syncthreads();

    ushort* dst = xrT + ((size_t)bt * Vdim + v0) * Edim;   // contiguous 32 KB
#pragma unroll
    for (int j = 0; j < 4; ++j) {
        const int q = tid + 256 * j;
        const int p = q >> 3;            // v-pair 0..127
        const int k = q & 7;             // e-octet 0..7
        uint lo[4], hi[4];
#pragma unroll
        for (int c = 0; c < 4; ++c) {
            const int ea = 8 * k + 2 * c;
            const int eb = ea + 1;
            const uint A = t[ea * 128 + (p ^ (((ea & 7) ^ ((ea >> 3) & 7)) << 2))];
            const uint B = t[eb * 128 + (p ^ (((eb & 7) ^ ((eb >> 3) & 7)) << 2))];
            lo[c] = (A & 0xffffu) | (B << 16);
            hi[c] = (A >> 16) | (B & 0xffff0000u);
        }
        uint4 o0, o1;
        o0.x = lo[0]; o0.y = lo[1]; o0.z = lo[2]; o0.w = lo[3];
        o1.x = hi[0]; o1.y = hi[1]; o1.z = hi[2]; o1.w = hi[3];
        *(uint4*)(dst + (size_t)((2 * p) * 8 + k) * 8)     = o0;
        *(uint4*)(dst + (size_t)((2 * p + 1) * 8 + k) * 8) = o1;
    }
}

// ---------------------------------------------------------------------------
// K3 (R8 structure + nontemporal W/out; ~118 us = HBM floor, measured R11).
// ---------------------------------------------------------------------------
__global__ __launch_bounds__(256, 4) void k_final(const ushort* __restrict__ xrT,
        const int* __restrict__ n_route, const int* __restrict__ s_week,
        const int* __restrict__ s_day,  const float* __restrict__ sape,
        const float* __restrict__ dow,  const float* __restrict__ tod,
        const float* __restrict__ Wc,   const float* __restrict__ bias,
        float* __restrict__ out) {
    __shared__ __align__(16) uint   Wt[2][64 * 36];   // bf16 [e][72f], word units
    __shared__ __align__(16) ushort xs[32 * 216];     // xl bf16 [b][f], pitch 216
    __shared__ float bl[64];
    const int tid = threadIdx.x;
    const int l = tid & 63, w = tid >> 6;
    const int v = blockIdx.x & (Vdim - 1);
    const int t = blockIdx.x >> 10;

    const float* Wg = Wc + ((size_t)(t * Vdim + v)) * 192 * Edim;
    const int i16  = tid & 15;           // e-quad group (cols 4*i16..+3)
    const int j16  = tid >> 4;           // f-quad group (rows 4*j16..+3 in chunk)
    const int colb = i16 * 4;
    const int swW  = (i16 & 3) << 2;     // f-word XOR key, = 4*((e>>2)&3)

    f32x4 wr0[4], wr1[4];
#pragma unroll
    for (int r = 0; r < 4; ++r)
        wr0[r] = __builtin_nontemporal_load((const f32x4*)(Wg + (size_t)(j16 * 4 + r) * Edim + colb));
#pragma unroll
    for (int r = 0; r < 4; ++r)
        wr1[r] = __builtin_nontemporal_load((const f32x4*)(Wg + (size_t)(64 + j16 * 4 + r) * Edim + colb));

    {
        const int b  = tid >> 3;
        const int e0 = (tid & 7) * 8;
        const int bt = b * Tdim + t;
        uint4 raw = *(const uint4*)(xrT + ((size_t)(bt * Vdim) + v) * Edim + e0);
        *(uint4*)&xs[b * 216 + e0] = raw;
        const int r  = n_route[b * Vdim + v];
        const float* sp = sape + ((size_t)(r * Tdim) + t) * Edim + e0;
        const int wd = s_week[bt], dd = s_day[bt];
        const float* dp = dow + ((size_t)(wd * Vdim) + v) * Edim + e0;
        const float* tp = tod + ((size_t)(dd * Vdim) + v) * Edim + e0;
        uint4 o1, o2;
        o1.x = pk2(sp[0], sp[1]); o1.y = pk2(sp[2], sp[3]);
        o1.z = pk2(sp[4], sp[5]); o1.w = pk2(sp[6], sp[7]);
        *(uint4*)&xs[b * 216 + 64 + e0] = o1;
        o2.x = pk2(dp[0] + tp[0], dp[1] + tp[1]);
        o2.y = pk2(dp[2] + tp[2], dp[3] + tp[3]);
        o2.z = pk2(dp[4] + tp[4], dp[5] + tp[5]);
        o2.w = pk2(dp[6] + tp[6], dp[7] + tp[7]);
        *(uint4*)&xs[b * 216 + 128 + e0] = o2;
    }
    if (tid < 64) bl[tid] = bias[((size_t)(t * Vdim) + v) * Edim + tid];

    auto wwrite = [&](int buf, const f32x4* wr) {
#pragma unroll
        for (int k = 0; k < 4; ++k) {
            const int e = colb + k;
            uint2 o;
            o.x = pk2(wr[0][k], wr[1][k]);
            o.y = pk2(wr[2][k], wr[3][k]);
            *(uint2*)&Wt[buf][e * 36 + ((2 * j16) ^ swW)] = o;
        }
    };

    const int mt  = w >> 1;              // b half
    const int ntb = (w & 1) * 2;         // e quarter base
    const f32x4 fz = {0.f, 0.f, 0.f, 0.f};
    f32x4 acc[2] = {fz, fz};
    const int arow = (mt * 16 + (l & 15)) * 216;
    const int g4   = (l >> 4);           // k-group 0..3

    auto computeChunk = [&](int buf, int ksb) {
#pragma unroll
        for (int kk = 0; kk < 2; ++kk) {
            bf16x8 aF = *(const bf16x8*)&xs[arow + (ksb + kk) * 32 + g4 * 8];
#pragma unroll
            for (int ni = 0; ni < 2; ++ni) {
                const int ecol = (ntb + ni) * 16 + (l & 15);
                const int swr  = ((ecol >> 2) & 3) << 2;
                uint4 u = *(const uint4*)&Wt[buf][ecol * 36 + 16 * kk + ((4 * g4) ^ swr)];
                bf16x8 bF;
                __builtin_memcpy(&bF, &u, 16);
                acc[ni] = __builtin_amdgcn_mfma_f32_16x16x32_bf16(aF, bF, acc[ni], 0, 0, 0);
            }
        }
    };

    wwrite(0, wr0);
    __syncthreads();
    f32x4 wr2[4];
#pragma unroll
    for (int r = 0; r < 4; ++r)
        wr2[r] = __builtin_nontemporal_load((const f32x4*)(Wg + (size_t)(128 + j16 * 4 + r) * Edim + colb));
    computeChunk(0, 0);
    wwrite(1, wr1);
    __syncthreads();
    computeChunk(1, 2);
    wwrite(0, wr2);
    __syncthreads();
    computeChunk(0, 4);

    const int brow = mt * 16 + g4 * 4;
#pragma unroll
    for (int ni = 0; ni < 2; ++ni) {
        const int ecol = (ntb + ni) * 16 + (l & 15);
        const float bv = bl[ecol];
#pragma unroll
        for (int j = 0; j < 4; ++j) {
            float s = acc[ni][j] + bv;
            s = s > 0.f ? s : 0.3f * s;
            __builtin_nontemporal_store(s,
                &out[(size_t)(brow + j) * (Tdim * Vdim * Edim)
                     + (size_t)t * (Vdim * Edim) + v * Edim + ecol]);
        }
    }
}

// ---------------------------------------------------------------------------
extern "C" void kernel_launch(void* const* d_in, const int* in_sizes, int n_in,
                              void* d_out, int out_size, void* d_ws, size_t ws_size,
                              hipStream_t stream) {
    const float* inputs = (const float*)d_in[0];
    const int*   n_route= (const int*)d_in[1];
    const int*   s_week = (const int*)d_in[2];
    const int*   s_day  = (const int*)d_in[3];
    const float* srpe   = (const float*)d_in[4];
    const float* sape   = (const float*)d_in[5];
    const float* dow    = (const float*)d_in[6];
    const float* tod    = (const float*)d_in[7];
    const float* Wc     = (const float*)d_in[8];
    const float* bias   = (const float*)d_in[9];

    // ws layout: Xbf [0, 48MB) ; Se [48MB, 52MB) ; xrT reuses [0, 48MB) after K2
    ushort* Xbf  = (ushort*)d_ws;
    ushort* Se   = (ushort*)((char*)d_ws + (size_t)Edim * BT * Vdim * 2);
    ushort* xrel = (ushort*)d_out;               // bf16 scratch inside d_out
    ushort* xrT  = (ushort*)d_ws;                // overwrites Xbf (dead after K2)
    float*  out  = (float*)d_out;

    k_xpose<<<dim3(BT * 16), dim3(256), 0, stream>>>(inputs, Xbf);
    k_se<<<dim3(Vdim / 8), dim3(256), 0, stream>>>(srpe, Se);
    k_relmix_mfma<<<dim3(1024), dim3(256), 0, stream>>>(Xbf, Se, xrel);
    k_xrelT<<<dim3(BT * 4), dim3(256), 0, stream>>>(xrel, xrT);
    k_final<<<dim3(Tdim * Vdim), dim3(256), 0, stream>>>(
        xrT, n_route, s_week, s_day, sape, dow, tod, Wc, bias, out);
}

// Round 16
// 257.437 us; speedup vs baseline: 4.0310x; 1.0060x over previous
//
#include <hip/hip_runtime.h>
#include <stdint.h>

#define Bdim 32
#define Tdim 12
#define Vdim 1024
#define Edim 64
#define Gdim 32
#define BT   384   // B*T

typedef __attribute__((ext_vector_type(8))) short bf16x8;
typedef __attribute__((ext_vector_type(4))) float f32x4;

// pk2(a,b): bf16(a) in low 16, bf16(b) in high 16 — single HW instr, RNE.
__device__ __forceinline__ uint pk2(float a, float b) {
    uint r;
    asm("v_cvt_pk_bf16_f32 %0, %1, %2" : "=v"(r) : "v"(a), "v"(b));
    return r;
}
__device__ __forceinline__ ushort f2bf(float f) {
    return (ushort)(pk2(f, f) & 0xffffu);
}

// ---------------------------------------------------------------------------
// K1a: Xbf[e][bt][i] (bf16) = inputs[bt][i][e] (f32).  ~10 us (measured R13).
// ---------------------------------------------------------------------------
__global__ __launch_bounds__(256) void k_xpose(const float* __restrict__ in,
                                               ushort* __restrict__ Xbf) {
    __shared__ float tile[64][69];
    const int bt = blockIdx.x >> 4;
    const int i0 = (blockIdx.x & 15) << 6;
    const int r  = threadIdx.x >> 2;     // i-local on load, e on store
    const int q  = threadIdx.x & 3;
    const float* src = in + ((size_t)(bt * Vdim) + i0 + r) * Edim + q * 16;
#pragma unroll
    for (int k = 0; k < 4; ++k) {
        float4 x = *(const float4*)(src + 4 * k);
        tile[r][q * 16 + 4 * k + 0] = x.x;
        tile[r][q * 16 + 4 * k + 1] = x.y;
        tile[r][q * 16 + 4 * k + 2] = x.z;
        tile[r][q * 16 + 4 * k + 3] = x.w;
    }
    __syncthreads();
    const int e  = r;
    const int ib = q * 16;
    uint4 s0, s1;
    s0.x = pk2(tile[ib + 0][e],  tile[ib + 1][e]);
    s0.y = pk2(tile[ib + 2][e],  tile[ib + 3][e]);
    s0.z = pk2(tile[ib + 4][e],  tile[ib + 5][e]);
    s0.w = pk2(tile[ib + 6][e],  tile[ib + 7][e]);
    s1.x = pk2(tile[ib + 8][e],  tile[ib + 9][e]);
    s1.y = pk2(tile[ib + 10][e], tile[ib + 11][e]);
    s1.z = pk2(tile[ib + 12][e], tile[ib + 13][e]);
    s1.w = pk2(tile[ib + 14][e], tile[ib + 15][e]);
    ushort* dst = Xbf + ((size_t)(e * BT) + bt) * Vdim + i0 + ib;
    *(uint4*)dst = s0;
    *(uint4*)(dst + 8) = s1;
}

// ---------------------------------------------------------------------------
// K1b: Se[e][v][g] (bf16) = srpe[v][g][e] (f32)
// ---------------------------------------------------------------------------
__global__ __launch_bounds__(256) void k_se(const float* __restrict__ srpe,
                                            ushort* __restrict__ Se) {
    __shared__ float t2[256][65];        // [vv*32+g][e], pad 65
    const int tid = threadIdx.x;
    const int v0 = blockIdx.x * 8;
#pragma unroll
    for (int c = 0; c < 16; ++c) {
        int f = (c * 256 + tid) * 4;     // flat f32 idx within block slab
        int vg = f >> 6;
        int e4 = f & 63;
        *(float4*)&t2[vg][e4] = *(const float4*)(srpe + (size_t)v0 * Gdim * Edim + f);
    }
    __syncthreads();
    const int e = tid & 63;
#pragma unroll
    for (int h = 0; h < 2; ++h) {
        const int vv = (tid >> 6) * 2 + h;
        uint4 o[2];
#pragma unroll
        for (int c = 0; c < 2; ++c) {
            o[c].x = pk2(t2[vv * 32 + c * 16 + 0][e],  t2[vv * 32 + c * 16 + 1][e]);
            o[c].y = pk2(t2[vv * 32 + c * 16 + 2][e],  t2[vv * 32 + c * 16 + 3][e]);
            o[c].z = pk2(t2[vv * 32 + c * 16 + 4][e],  t2[vv * 32 + c * 16 + 5][e]);
            o[c].w = pk2(t2[vv * 32 + c * 16 + 6][e],  t2[vv * 32 + c * 16 + 7][e]);
        }
        uint4 o2[2];
#pragma unroll
        for (int c = 0; c < 2; ++c) {
            o2[c].x = pk2(t2[vv * 32 + c * 16 + 8][e],  t2[vv * 32 + c * 16 + 9][e]);
            o2[c].y = pk2(t2[vv * 32 + c * 16 + 10][e], t2[vv * 32 + c * 16 + 11][e]);
            o2[c].z = pk2(t2[vv * 32 + c * 16 + 12][e], t2[vv * 32 + c * 16 + 13][e]);
            o2[c].w = pk2(t2[vv * 32 + c * 16 + 14][e], t2[vv * 32 + c * 16 + 15][e]);
        }
        ushort* dst = Se + ((size_t)(e * Vdim) + v0 + vv) * Gdim;
        *(uint4*)(dst + 0)  = o[0];
        *(uint4*)(dst + 8)  = o2[0];
        *(uint4*)(dst + 16) = o[1];
        *(uint4*)(dst + 24) = o2[1];
    }
}

// ---------------------------------------------------------------------------
// K2 v4: occupancy round.  A_s 2-buf (depth-1: step ~1us >> HBM latency),
// Si_s 3-slot ring (computeR at t reads Si[t+1], issued t-1, drained by the
// end-of-(t-1) vmcnt(0)).  LDS 50 KB -> 3 wg/CU (was 62 KB -> 2).
// Full XOR swizzle.  One vmcnt(0)+lgkmcnt(0) barrier per step.
// ---------------------------------------------------------------------------
__global__ __launch_bounds__(256, 3) void k_relmix_mfma(const ushort* __restrict__ Xbf,
                                                        const ushort* __restrict__ Se,
                                                        ushort* __restrict__ xrel) {
    __shared__ __align__(16) ushort A_s[2][192 * 32];   // [bt][i], src-swizzled
    __shared__ __align__(16) ushort Si_s[3][32 * 32];   // [i][g],  src-swizzled
    __shared__ __align__(16) ushort R_s[2][128 * 40];   // [v][i],  80 B pitch

    const int tid = threadIdx.x;
    const int l = tid & 63;
    const int w = tid >> 6;              // wave 0..3
    const int wm = w >> 1;               // bt half (96 each)
    const int wn = w & 1;                // v half (64 each)

    const int raw = blockIdx.x;                       // 0..1023
    const int wg  = (raw & 7) * 128 + (raw >> 3);     // bijective XCD chunking
    const int e   = wg >> 4;
    const int btT = (wg >> 3) & 1;
    const int vT  = wg & 7;
    const int bt0 = btT * 192;
    const int v0  = vT * 128;

    const int lr  = l >> 2;                           // sub-row in 16-row chunk
    const int lc  = ((l & 3) ^ (lr & 3) ^ ((lr >> 2) & 3)) * 8;  // FULL swizzle

    const ushort* gA  = Xbf + ((size_t)(e * BT + bt0)) * Vdim;
    const ushort* gSi = Se + (size_t)e * Vdim * Gdim;

    bf16x8 svF[2];
    {
        const ushort* gSv = Se + ((size_t)e * Vdim + v0) * Gdim;
#pragma unroll
        for (int k = 0; k < 2; ++k) {
            const int vloc = (2 * w + k) * 16 + (l & 15);
            svF[k] = *(const bf16x8*)(gSv + (size_t)vloc * Gdim + (l >> 4) * 8);
        }
    }
    __builtin_amdgcn_sched_barrier(0);

    // ---- prologue: Si tile0 -> slot0, A tile0 -> buf0, Si tile1 -> slot1
    if (w < 2)
        __builtin_amdgcn_global_load_lds(gSi + (size_t)(0 + w * 16 + lr) * Gdim + lc,
                                         &Si_s[0][w * 512], 16, 0, 0);
#pragma unroll
    for (int c = 0; c < 3; ++c) {
        int chunk = w * 3 + c;
        __builtin_amdgcn_global_load_lds(gA + (size_t)(chunk * 16 + lr) * Vdim + 0 + lc,
                                         &A_s[0][chunk * 512], 16, 0, 0);
    }
    if (w < 2)
        __builtin_amdgcn_global_load_lds(gSi + (size_t)(32 + w * 16 + lr) * Gdim + lc,
                                         &Si_s[1][w * 512], 16, 0, 0);
    asm volatile("s_waitcnt vmcnt(0)" ::: "memory");
    __builtin_amdgcn_sched_barrier(0);
    __builtin_amdgcn_s_barrier();
    __builtin_amdgcn_sched_barrier(0);

    const f32x4 fz = {0.f, 0.f, 0.f, 0.f};

    auto computeR = [&](int sb, int rb) {
        const int r0 = (l & 15), r1 = 16 + (l & 15);
        const int kg = l >> 4;
        const int k0 = (kg ^ (r0 & 3) ^ ((r0 >> 2) & 3)) * 8;   // r1 shares key
        bf16x8 siF0 = *(const bf16x8*)&Si_s[sb][r0 * 32 + k0];
        bf16x8 siF1 = *(const bf16x8*)&Si_s[sb][r1 * 32 + k0];
#pragma unroll
        for (int k = 0; k < 2; ++k) {
            const int vloc = (2 * w + k) * 16 + (l & 15);
            f32x4 d0 = __builtin_amdgcn_mfma_f32_16x16x32_bf16(siF0, svF[k], fz, 0, 0, 0);
            f32x4 d1 = __builtin_amdgcn_mfma_f32_16x16x32_bf16(siF1, svF[k], fz, 0, 0, 0);
            uint2 w0, w1;
            w0.x = pk2(fmaxf(d0[0], 0.f), fmaxf(d0[1], 0.f));
            w0.y = pk2(fmaxf(d0[2], 0.f), fmaxf(d0[3], 0.f));
            w1.x = pk2(fmaxf(d1[0], 0.f), fmaxf(d1[1], 0.f));
            w1.y = pk2(fmaxf(d1[2], 0.f), fmaxf(d1[3], 0.f));
            *(uint2*)&R_s[rb][vloc * 40 + kg * 4]      = w0;
            *(uint2*)&R_s[rb][vloc * 40 + 16 + kg * 4] = w1;
        }
    };

    // prologue R for step 0 (from Si slot 0; landed above)
    computeR(0, 0);
    asm volatile("s_waitcnt lgkmcnt(0)" ::: "memory");
    __builtin_amdgcn_sched_barrier(0);
    __builtin_amdgcn_s_barrier();
    __builtin_amdgcn_sched_barrier(0);

    f32x4 acc[6][4];
#pragma unroll
    for (int m = 0; m < 6; ++m)
#pragma unroll
        for (int n = 0; n < 4; ++n) acc[m][n] = fz;

    int rc = 0, rn = 1;

    for (int t = 0; t < 32; ++t) {
        // ---- issue A[t+1] into buf (t+1)&1 (wrap at tail: valid, never read)
        const int ia = ((t + 1) & 31) * 32;
#pragma unroll
        for (int c = 0; c < 3; ++c) {
            int chunk = w * 3 + c;
            __builtin_amdgcn_global_load_lds(gA + (size_t)(chunk * 16 + lr) * Vdim + ia + lc,
                                             &A_s[(t + 1) & 1][chunk * 512], 16, 0, 0);
        }
        // ---- issue Si[t+2] into slot (t+2)%3 (wrap at tail)
        {
            const int is = ((t + 2) & 31) * 32;
            if (w < 2)
                __builtin_amdgcn_global_load_lds(gSi + (size_t)(is + w * 16 + lr) * Gdim + lc,
                                                 &Si_s[(t + 2) % 3][w * 512], 16, 0, 0);
        }
        // ---- R for step t+1 from Si slot (t+1)%3 (issued t-1, landed)
        computeR((t + 1) % 3, rn);
        // ---- A fragments from current buffer (landed end of t-1)
        bf16x8 aF[6];
#pragma unroll
        for (int m = 0; m < 6; ++m) {
            const int row = wm * 96 + m * 16 + (l & 15);
            const int key = ((l >> 4) ^ (row & 3) ^ ((row >> 2) & 3)) * 8;
            aF[m] = *(const bf16x8*)&A_s[t & 1][row * 32 + key];
        }
        // ---- 24 main MFMAs reading R_s[rc] (computed last step)
        __builtin_amdgcn_s_setprio(1);
#pragma unroll
        for (int n = 0; n < 4; ++n) {
            bf16x8 bF = *(const bf16x8*)&R_s[rc][(wn * 64 + n * 16 + (l & 15)) * 40 + (l >> 4) * 8];
#pragma unroll
            for (int m = 0; m < 6; ++m)
                acc[m][n] = __builtin_amdgcn_mfma_f32_16x16x32_bf16(aF[m], bF, acc[m][n], 0, 0, 0);
        }
        __builtin_amdgcn_s_setprio(0);
        // ---- single barrier: all this step's loads landed, LDS drained
        asm volatile("s_waitcnt vmcnt(0) lgkmcnt(0)" ::: "memory");
        __builtin_amdgcn_sched_barrier(0);
        __builtin_amdgcn_s_barrier();
        __builtin_amdgcn_sched_barrier(0);
        int tmp = rc; rc = rn; rn = tmp;
    }

    // ---- epilogue: bf16 stores, v-contiguous across lanes (32 B runs)
#pragma unroll
    for (int m = 0; m < 6; ++m) {
        const int btl = bt0 + wm * 96 + m * 16 + (l >> 4) * 4;
#pragma unroll
        for (int j = 0; j < 4; ++j) {
            ushort* row = xrel + ((size_t)(e * BT) + btl + j) * Vdim + v0;
#pragma unroll
            for (int n = 0; n < 4; ++n)
                row[wn * 64 + n * 16 + (l & 15)] = f2bf(acc[m][n][j]);
        }
    }
}

// ---------------------------------------------------------------------------
// K2.5 v3: xrT[bt][v][e] = xrel[e][bt][v].  32 KB LDS, 1536 wgs, coalesced.
// ---------------------------------------------------------------------------
__global__ __launch_bounds__(256) void k_xrelT(const ushort* __restrict__ xr,
                                               ushort* __restrict__ xrT) {
    __shared__ uint t[64 * 128];         // word (e, v-pair local), swizzled
    const int tid = threadIdx.x;
    const int l = tid & 63, w = tid >> 6;
    const int bt = blockIdx.x >> 2;
    const int v0 = (blockIdx.x & 3) * 256;

#pragma unroll
    for (int i = 0; i < 8; ++i) {
        const int e = w * 16 + 2 * i + (l >> 5);
        const int key = ((e & 7) ^ ((e >> 3) & 7)) << 2;
        uint4 x = *(const uint4*)(xr + ((size_t)(e * BT) + bt) * Vdim + v0 + (l & 31) * 8);
        *(uint4*)&t[e * 128 + ((((l & 31) * 4)) ^ key)] = x;
    }
    __syncthreads();

    ushort* dst = xrT + ((size_t)bt * Vdim + v0) * Edim;   // contiguous 32 KB
#pragma unroll
    for (int j = 0; j < 4; ++j) {
        const int q = tid + 256 * j;
        const int p = q >> 3;            // v-pair 0..127
        const int k = q & 7;             // e-octet 0..7
        uint lo[4], hi[4];
#pragma unroll
        for (int c = 0; c < 4; ++c) {
            const int ea = 8 * k + 2 * c;
            const int eb = ea + 1;
            const uint A = t[ea * 128 + (p ^ (((ea & 7) ^ ((ea >> 3) & 7)) << 2))];
            const uint B = t[eb * 128 + (p ^ (((eb & 7) ^ ((eb >> 3) & 7)) << 2))];
            lo[c] = (A & 0xffffu) | (B << 16);
            hi[c] = (A >> 16) | (B & 0xffff0000u);
        }
        uint4 o0, o1;
        o0.x = lo[0]; o0.y = lo[1]; o0.z = lo[2]; o0.w = lo[3];
        o1.x = hi[0]; o1.y = hi[1]; o1.z = hi[2]; o1.w = hi[3];
        *(uint4*)(dst + (size_t)((2 * p) * 8 + k) * 8)     = o0;
        *(uint4*)(dst + (size_t)((2 * p + 1) * 8 + k) * 8) = o1;
    }
}

// ---------------------------------------------------------------------------
// K3 (R8 structure + nontemporal W/out; ~118 us = HBM floor, measured R11).
// ---------------------------------------------------------------------------
__global__ __launch_bounds__(256, 4) void k_final(const ushort* __restrict__ xrT,
        const int* __restrict__ n_route, const int* __restrict__ s_week,
        const int* __restrict__ s_day,  const float* __restrict__ sape,
        const float* __restrict__ dow,  const float* __restrict__ tod,
        const float* __restrict__ Wc,   const float* __restrict__ bias,
        float* __restrict__ out) {
    __shared__ __align__(16) uint   Wt[2][64 * 36];   // bf16 [e][72f], word units
    __shared__ __align__(16) ushort xs[32 * 216];     // xl bf16 [b][f], pitch 216
    __shared__ float bl[64];
    const int tid = threadIdx.x;
    const int l = tid & 63, w = tid >> 6;
    const int v = blockIdx.x & (Vdim - 1);
    const int t = blockIdx.x >> 10;

    const float* Wg = Wc + ((size_t)(t * Vdim + v)) * 192 * Edim;
    const int i16  = tid & 15;           // e-quad group (cols 4*i16..+3)
    const int j16  = tid >> 4;           // f-quad group (rows 4*j16..+3 in chunk)
    const int colb = i16 * 4;
    const int swW  = (i16 & 3) << 2;     // f-word XOR key, = 4*((e>>2)&3)

    f32x4 wr0[4], wr1[4];
#pragma unroll
    for (int r = 0; r < 4; ++r)
        wr0[r] = __builtin_nontemporal_load((const f32x4*)(Wg + (size_t)(j16 * 4 + r) * Edim + colb));
#pragma unroll
    for (int r = 0; r < 4; ++r)
        wr1[r] = __builtin_nontemporal_load((const f32x4*)(Wg + (size_t)(64 + j16 * 4 + r) * Edim + colb));

    {
        const int b  = tid >> 3;
        const int e0 = (tid & 7) * 8;
        const int bt = b * Tdim + t;
        uint4 raw = *(const uint4*)(xrT + ((size_t)(bt * Vdim) + v) * Edim + e0);
        *(uint4*)&xs[b * 216 + e0] = raw;
        const int r  = n_route[b * Vdim + v];
        const float* sp = sape + ((size_t)(r * Tdim) + t) * Edim + e0;
        const int wd = s_week[bt], dd = s_day[bt];
        const float* dp = dow + ((size_t)(wd * Vdim) + v) * Edim + e0;
        const float* tp = tod + ((size_t)(dd * Vdim) + v) * Edim + e0;
        uint4 o1, o2;
        o1.x = pk2(sp[0], sp[1]); o1.y = pk2(sp[2], sp[3]);
        o1.z = pk2(sp[4], sp[5]); o1.w = pk2(sp[6], sp[7]);
        *(uint4*)&xs[b * 216 + 64 + e0] = o1;
        o2.x = pk2(dp[0] + tp[0], dp[1] + tp[1]);
        o2.y = pk2(dp[2] + tp[2], dp[3] + tp[3]);
        o2.z = pk2(dp[4] + tp[4], dp[5] + tp[5]);
        o2.w = pk2(dp[6] + tp[6], dp[7] + tp[7]);
        *(uint4*)&xs[b * 216 + 128 + e0] = o2;
    }
    if (tid < 64) bl[tid] = bias[((size_t)(t * Vdim) + v) * Edim + tid];

    auto wwrite = [&](int buf, const f32x4* wr) {
#pragma unroll
        for (int k = 0; k < 4; ++k) {
            const int e = colb + k;
            uint2 o;
            o.x = pk2(wr[0][k], wr[1][k]);
            o.y = pk2(wr[2][k], wr[3][k]);
            *(uint2*)&Wt[buf][e * 36 + ((2 * j16) ^ swW)] = o;
        }
    };

    const int mt  = w >> 1;              // b half
    const int ntb = (w & 1) * 2;         // e quarter base
    const f32x4 fz = {0.f, 0.f, 0.f, 0.f};
    f32x4 acc[2] = {fz, fz};
    const int arow = (mt * 16 + (l & 15)) * 216;
    const int g4   = (l >> 4);           // k-group 0..3

    auto computeChunk = [&](int buf, int ksb) {
#pragma unroll
        for (int kk = 0; kk < 2; ++kk) {
            bf16x8 aF = *(const bf16x8*)&xs[arow + (ksb + kk) * 32 + g4 * 8];
#pragma unroll
            for (int ni = 0; ni < 2; ++ni) {
                const int ecol = (ntb + ni) * 16 + (l & 15);
                const int swr  = ((ecol >> 2) & 3) << 2;
                uint4 u = *(const uint4*)&Wt[buf][ecol * 36 + 16 * kk + ((4 * g4) ^ swr)];
                bf16x8 bF;
                __builtin_memcpy(&bF, &u, 16);
                acc[ni] = __builtin_amdgcn_mfma_f32_16x16x32_bf16(aF, bF, acc[ni], 0, 0, 0);
            }
        }
    };

    wwrite(0, wr0);
    __syncthreads();
    f32x4 wr2[4];
#pragma unroll
    for (int r = 0; r < 4; ++r)
        wr2[r] = __builtin_nontemporal_load((const f32x4*)(Wg + (size_t)(128 + j16 * 4 + r) * Edim + colb));
    computeChunk(0, 0);
    wwrite(1, wr1);
    __syncthreads();
    computeChunk(1, 2);
    wwrite(0, wr2);
    __syncthreads();
    computeChunk(0, 4);

    const int brow = mt * 16 + g4 * 4;
#pragma unroll
    for (int ni = 0; ni < 2; ++ni) {
        const int ecol = (ntb + ni) * 16 + (l & 15);
        const float bv = bl[ecol];
#pragma unroll
        for (int j = 0; j < 4; ++j) {
            float s = acc[ni][j] + bv;
            s = s > 0.f ? s : 0.3f * s;
            __builtin_nontemporal_store(s,
                &out[(size_t)(brow + j) * (Tdim * Vdim * Edim)
                     + (size_t)t * (Vdim * Edim) + v * Edim + ecol]);
        }
    }
}

// ---------------------------------------------------------------------------
extern "C" void kernel_launch(void* const* d_in, const int* in_sizes, int n_in,
                              void* d_out, int out_size, void* d_ws, size_t ws_size,
                              hipStream_t stream) {
    const float* inputs = (const float*)d_in[0];
    const int*   n_route= (const int*)d_in[1];
    const int*   s_week = (const int*)d_in[2];
    const int*   s_day  = (const int*)d_in[3];
    const float* srpe   = (const float*)d_in[4];
    const float* sape   = (const float*)d_in[5];
    const float* dow    = (const float*)d_in[6];
    const float* tod    = (const float*)d_in[7];
    const float* Wc     = (const float*)d_in[8];
    const float* bias   = (const float*)d_in[9];

    // ws layout: Xbf [0, 48MB) ; Se [48MB, 52MB) ; xrT reuses [0, 48MB) after K2
    ushort* Xbf  = (ushort*)d_ws;
    ushort* Se   = (ushort*)((char*)d_ws + (size_t)Edim * BT * Vdim * 2);
    ushort* xrel = (ushort*)d_out;               // bf16 scratch inside d_out
    ushort* xrT  = (ushort*)d_ws;                // overwrites Xbf (dead after K2)
    float*  out  = (float*)d_out;

    k_xpose<<<dim3(BT * 16), dim3(256), 0, stream>>>(inputs, Xbf);
    k_se<<<dim3(Vdim / 8), dim3(256), 0, stream>>>(srpe, Se);
    k_relmix_mfma<<<dim3(1024), dim3(256), 0, stream>>>(Xbf, Se, xrel);
    k_xrelT<<<dim3(BT * 4), dim3(256), 0, stream>>>(xrel, xrT);
    k_final<<<dim3(Tdim * Vdim), dim3(256), 0, stream>>>(
        xrT, n_route, s_week, s_day, sape, dow, tod, Wc, bias, out);
}